// Round 1
// baseline (92.523 us; speedup 1.0000x reference)
//
#include <hip/hip_runtime.h>
#include <math.h>

#define CC 8
#define PP 169
#define KTOT 100
#define WW 128
#define HWSZ (128*128)
#define KCH 50          // instances per block (k-chunk)

// param layout per instance (169 floats):
//  [0:80)    w0  (8 x 10) row-major
//  [80:144)  w1  (8 x 8)  row-major
//  [144:152) w2  (8)
//  [152:160) b0
//  [160:168) b1
//  [168]     b2

__global__ __launch_bounds__(256) void condinst_kernel(
    const float* __restrict__ seg_feat,     // (B, C, HW)
    const float* __restrict__ conv_weight,  // (B, P, HW)
    const int*   __restrict__ ind,          // (B, K)
    float*       __restrict__ out)          // (B, K, HW)
{
    __shared__ float sp[KCH][PP];
    __shared__ float sx[KCH];
    __shared__ float sy[KCH];

    const int tile = blockIdx.x;   // 0..63
    const int b    = blockIdx.y;   // 0..3
    const int kc   = blockIdx.z;   // 0..1
    const int k0   = kc * KCH;
    const int px   = tile * 256 + threadIdx.x;

    // ---- stage this chunk's instance params into LDS ----
    for (int i = threadIdx.x; i < KCH * PP; i += 256) {
        int k = i / PP;
        int p = i - k * PP;
        int hw = ind[b * KTOT + k0 + k];
        sp[k][p] = conv_weight[(size_t)(b * PP + p) * HWSZ + hw];
    }
    if (threadIdx.x < KCH) {
        int hw = ind[b * KTOT + k0 + threadIdx.x];
        sx[threadIdx.x] = (float)(hw % WW);
        sy[threadIdx.x] = (float)(hw / WW);
    }
    __syncthreads();

    // ---- per-pixel state (loaded once, reused for all 50 instances) ----
    float feat[CC];
    #pragma unroll
    for (int c = 0; c < CC; ++c)
        feat[c] = seg_feat[(size_t)(b * CC + c) * HWSZ + px];

    const float xp = (float)(px & (WW - 1));
    const float yp = (float)(px >> 7);

    float* outp = out + (size_t)(b * KTOT + k0) * HWSZ + px;

    for (int k = 0; k < KCH; ++k) {
        const float* p = sp[k];
        const float relx = (sx[k] - xp) * 0.0078125f;   // /128
        const float rely = (sy[k] - yp) * 0.0078125f;

        float h0[CC];
        #pragma unroll
        for (int o = 0; o < CC; ++o) {
            float acc = p[152 + o];
            acc = fmaf(p[o * 10 + 0], relx, acc);
            acc = fmaf(p[o * 10 + 1], rely, acc);
            #pragma unroll
            for (int c = 0; c < CC; ++c)
                acc = fmaf(p[o * 10 + 2 + c], feat[c], acc);
            h0[o] = fmaxf(acc, 0.0f);
        }

        float h1[CC];
        #pragma unroll
        for (int o = 0; o < CC; ++o) {
            float acc = p[160 + o];
            #pragma unroll
            for (int c = 0; c < CC; ++c)
                acc = fmaf(p[80 + o * 8 + c], h0[c], acc);
            h1[o] = fmaxf(acc, 0.0f);
        }

        float z = p[168];
        #pragma unroll
        for (int c = 0; c < CC; ++c)
            z = fmaf(p[144 + c], h1[c], z);

        outp[(size_t)k * HWSZ] = 1.0f / (1.0f + __expf(-z));
    }
}

extern "C" void kernel_launch(void* const* d_in, const int* in_sizes, int n_in,
                              void* d_out, int out_size, void* d_ws, size_t ws_size,
                              hipStream_t stream) {
    const float* seg_feat    = (const float*)d_in[0];
    const float* conv_weight = (const float*)d_in[1];
    const int*   ind         = (const int*)d_in[2];
    float*       out         = (float*)d_out;

    dim3 grid(64, 4, 2);   // 64 pixel tiles x B x 2 k-chunks
    dim3 block(256);
    condinst_kernel<<<grid, block, 0, stream>>>(seg_feat, conv_weight, ind, out);
}

// Round 2
// 48.802 us; speedup vs baseline: 1.8959x; 1.8959x over previous
//
#include <hip/hip_runtime.h>
#include <math.h>

#define CC 8
#define PP 169
#define KTOT 100
#define WW 128
#define HWSZ (128*128)
#define KCH 10          // instances per block chunk (100 = 10 chunks)
#define FPI 204         // floats per instance in LDS: 17 rows x 12 floats

// LDS per-instance layout, 17 rows of 12 floats (each row 48B, 16B-aligned):
//  rows 0..7  : [ w0[o][0..9], b0[o], pad ]
//  rows 8..15 : [ w1[o][0..7], b1[o], pad, pad, pad ]
//  row  16    : [ w2[0..7],    b2,    pad, pad, pad ]

__global__ __launch_bounds__(256) void condinst_kernel(
    const float* __restrict__ seg_feat,     // (B, C, HW)
    const float* __restrict__ conv_weight,  // (B, P, HW)
    const int*   __restrict__ ind,          // (B, K)
    float*       __restrict__ out)          // (B, K, HW)
{
    __shared__ __align__(16) float sp[KCH * FPI];
    __shared__ float sx[KCH], sy[KCH];

    const int tile = blockIdx.x;   // 0..15 (1024 px per block)
    const int b    = blockIdx.y;   // 0..3
    const int k0   = blockIdx.z * KCH;

    // ---- stage + repack params into LDS ----
    for (int i = threadIdx.x; i < KCH * FPI; i += 256) {
        int k   = i / FPI;
        int rem = i - k * FPI;
        int r   = rem / 12;
        int col = rem - r * 12;
        int p = -1;
        if (r < 8) {
            if (col < 10)      p = r * 10 + col;
            else if (col == 10) p = 152 + r;
        } else if (r < 16) {
            int o = r - 8;
            if (col < 8)       p = 80 + o * 8 + col;
            else if (col == 8) p = 160 + o;
        } else {
            if (col < 8)       p = 144 + col;
            else if (col == 8) p = 168;
        }
        float v = 0.0f;
        if (p >= 0) {
            int hw = ind[b * KTOT + k0 + k];
            v = conv_weight[(size_t)(b * PP + p) * HWSZ + hw];
        }
        sp[i] = v;
    }
    if (threadIdx.x < KCH) {
        int hw = ind[b * KTOT + k0 + threadIdx.x];
        sx[threadIdx.x] = (float)(hw & (WW - 1));
        sy[threadIdx.x] = (float)(hw >> 7);
    }
    __syncthreads();

    // ---- 4 adjacent pixels per thread, loaded once ----
    const int px0 = tile * 1024 + threadIdx.x * 4;
    float ff[CC][4];
    #pragma unroll
    for (int c = 0; c < CC; ++c) {
        float4 v = *(const float4*)&seg_feat[(size_t)(b * CC + c) * HWSZ + px0];
        ff[c][0] = v.x; ff[c][1] = v.y; ff[c][2] = v.z; ff[c][3] = v.w;
    }

    const float x0 = (float)(px0 & (WW - 1));   // px0 % 4 == 0, so x0..x0+3 same row
    const float yp = (float)(px0 >> 7);

    for (int k = 0; k < KCH; ++k) {
        const float4* pr = (const float4*)(sp + k * FPI);
        float rx[4];
        rx[0] = (sx[k] - x0) * 0.0078125f;
        rx[1] = rx[0] - 0.0078125f;
        rx[2] = rx[0] - 0.015625f;
        rx[3] = rx[0] - 0.0234375f;
        const float ry = (sy[k] - yp) * 0.0078125f;

        float h0[CC][4];
        #pragma unroll
        for (int o = 0; o < CC; ++o) {
            float4 wa = pr[o * 3 + 0];   // wx, wy, wf0, wf1
            float4 wb = pr[o * 3 + 1];   // wf2..wf5
            float4 wc = pr[o * 3 + 2];   // wf6, wf7, b0, pad
            #pragma unroll
            for (int t = 0; t < 4; ++t) {
                float a = fmaf(wa.x, rx[t], wc.z);
                a = fmaf(wa.y, ry,       a);
                a = fmaf(wa.z, ff[0][t], a);
                a = fmaf(wa.w, ff[1][t], a);
                a = fmaf(wb.x, ff[2][t], a);
                a = fmaf(wb.y, ff[3][t], a);
                a = fmaf(wb.z, ff[4][t], a);
                a = fmaf(wb.w, ff[5][t], a);
                a = fmaf(wc.x, ff[6][t], a);
                a = fmaf(wc.y, ff[7][t], a);
                h0[o][t] = fmaxf(a, 0.0f);
            }
        }

        float h1[CC][4];
        #pragma unroll
        for (int o = 0; o < CC; ++o) {
            float4 ua = pr[24 + o * 3 + 0];  // w1[0..3]
            float4 ub = pr[24 + o * 3 + 1];  // w1[4..7]
            float4 uc = pr[24 + o * 3 + 2];  // b1, pad, pad, pad
            #pragma unroll
            for (int t = 0; t < 4; ++t) {
                float a = fmaf(ua.x, h0[0][t], uc.x);
                a = fmaf(ua.y, h0[1][t], a);
                a = fmaf(ua.z, h0[2][t], a);
                a = fmaf(ua.w, h0[3][t], a);
                a = fmaf(ub.x, h0[4][t], a);
                a = fmaf(ub.y, h0[5][t], a);
                a = fmaf(ub.z, h0[6][t], a);
                a = fmaf(ub.w, h0[7][t], a);
                h1[o][t] = fmaxf(a, 0.0f);
            }
        }

        float4 va = pr[48];  // w2[0..3]
        float4 vb = pr[49];  // w2[4..7]
        float4 vc = pr[50];  // b2, pad, pad, pad
        float4 res;
        float* resp = (float*)&res;
        #pragma unroll
        for (int t = 0; t < 4; ++t) {
            float z = fmaf(va.x, h1[0][t], vc.x);
            z = fmaf(va.y, h1[1][t], z);
            z = fmaf(va.z, h1[2][t], z);
            z = fmaf(va.w, h1[3][t], z);
            z = fmaf(vb.x, h1[4][t], z);
            z = fmaf(vb.y, h1[5][t], z);
            z = fmaf(vb.z, h1[6][t], z);
            z = fmaf(vb.w, h1[7][t], z);
            resp[t] = 1.0f / (1.0f + __expf(-z));
        }
        *(float4*)&out[(size_t)(b * KTOT + k0 + k) * HWSZ + px0] = res;
    }
}

extern "C" void kernel_launch(void* const* d_in, const int* in_sizes, int n_in,
                              void* d_out, int out_size, void* d_ws, size_t ws_size,
                              hipStream_t stream) {
    const float* seg_feat    = (const float*)d_in[0];
    const float* conv_weight = (const float*)d_in[1];
    const int*   ind         = (const int*)d_in[2];
    float*       out         = (float*)d_out;

    dim3 grid(16, 4, 10);   // 16 pixel tiles x B x 10 k-chunks
    dim3 block(256);
    condinst_kernel<<<grid, block, 0, stream>>>(seg_feat, conv_weight, ind, out);
}